// Round 19
// baseline (64.825 us; speedup 1.0000x reference)
//
#include <hip/hip_runtime.h>
#include <hip/hip_bf16.h>

// B=8192 rows, N=64 nodes, C=256. Per node: MLP 1->C->C->1 on s=Q*Y, then
// softmax over [z0, z_1..z_64]. Output f32 [B, 65].
//
// Round 19: byte-identical revert to R17 (passed, 64.7us; R15-family 63.6us).
// R18's "identical-arithmetic" eval batching failed correctness -> either a
// miscompile of that construct or a latent race; this run isolates which.

typedef unsigned int u32;
typedef __fp16 fp16x2 __attribute__((ext_vector_type(2)));
union U32H { u32 u; fp16x2 h; };

__device__ __forceinline__ u32 pkh(float a, float b) {   // lo=f16(a), hi=f16(b)
    U32H cv; cv.h = __builtin_amdgcn_cvt_pkrtz(a, b); return cv.u;
}
__device__ __forceinline__ float dot2f(u32 a, u32 b, float c) {
    float d;
    asm("v_dot2_f32_f16 %0, %1, %2, %3" : "=v"(d) : "v"(a), "v"(b), "v"(c));
    return d;
}

// ---------------------------------------------------------------------------
// K1: prep. blocks 0..127: S[n][b] = Q[b][n]*Y[b][n] (64x64 LDS transpose).
//           blocks 128..191: knee s*_k = -b1_k/w1_k + bitonic sort.
// ---------------------------------------------------------------------------
__global__ __launch_bounds__(256) void prep(
    const float* __restrict__ Q, const float* __restrict__ Y,
    const float* __restrict__ W1, const float* __restrict__ b1,
    float* __restrict__ S, float* __restrict__ knots, int* __restrict__ perm)
{
    __shared__ float ts[64][65];
    __shared__ float key[256];
    __shared__ int   idx[256];

    const int blk = blockIdx.x;
    const int tid = threadIdx.x;

    if (blk < 128) {
        const int b0 = blk << 6;
        #pragma unroll
        for (int jj = 0; jj < 16; jj++) {
            int i = tid + (jj << 8);
            int r = i >> 6, c = i & 63;
            ts[r][c] = Q[(size_t)(b0 + r) * 64 + c] * Y[(size_t)(b0 + r) * 64 + c];
        }
        __syncthreads();
        #pragma unroll
        for (int jj = 0; jj < 16; jj++) {
            int i = tid + (jj << 8);
            int nn = i >> 6, bb = i & 63;
            S[((size_t)nn << 13) + b0 + bb] = ts[bb][nn];
        }
    } else {
        const int n = blk - 128;
        {
            float w = W1[n * 256 + tid];
            float b = b1[n * 256 + tid];
            key[tid] = -b / w;           // +-inf when w ~ 0: sorts to the ends
            idx[tid] = tid;
        }
        __syncthreads();
        for (int k = 2; k <= 256; k <<= 1) {
            for (int j = k >> 1; j > 0; j >>= 1) {
                int p = tid ^ j;
                if (p > tid) {
                    float a = key[tid], c = key[p];
                    bool up = ((tid & k) == 0);
                    if (up ? (a > c) : (a < c)) {
                        int ia = idx[tid];
                        key[tid] = c; idx[tid] = idx[p];
                        key[p] = a; idx[p] = ia;
                    }
                }
                __syncthreads();
            }
        }
        knots[n * 256 + tid] = key[tid];
        perm[n * 256 + tid]  = idx[tid];
    }
}

// ---------------------------------------------------------------------------
// K2: build_sort.
// blocks 0..511: segmented-scan table build; (n = blk>>3, strip = blk&7).
// blocks 512..767: sort one (node, quarter) of samples by interval.
// ---------------------------------------------------------------------------
__global__ __launch_bounds__(256) void build_sort(
    const float* __restrict__ W1, const float* __restrict__ b1,
    const float* __restrict__ W2, const float* __restrict__ b2,
    const int* __restrict__ perm, const float* __restrict__ S,
    const float* __restrict__ knots,
    uint2* __restrict__ table, uint2* __restrict__ sorted)
{
    __shared__ float w1s[256], b1s[256];
    __shared__ int   pm[256];
    __shared__ float part[16][16][8];
    __shared__ u32   hist[257];

    const int blk = blockIdx.x;
    const int tid = threadIdx.x;
    const int lane = tid & 63;

    if (blk < 512) {
        // ================= scan_build role =================
        const int n    = blk >> 3;
        const int strip= blk & 7;
        const int prl  = tid & 15;
        const int seg  = tid >> 4;
        const int prg  = (strip << 4) + prl;
        const int d0   = prg << 1;

        w1s[tid] = W1[n * 256 + tid];
        b1s[tid] = b1[n * 256 + tid];
        pm[tid]  = perm[n * 256 + tid];
        __syncthreads();

        const float* W2n = W2 + ((size_t)n << 16);
        float2 vreg[16];                 // phase-1 W2 cache, reused in phase 3

        // phase 1: per-segment partials (cache W2 loads in regs)
        {
            float ba0 = 0.f, bc0 = 0.f, ba1 = 0.f, bc1 = 0.f;
            float da0 = 0.f, dc0 = 0.f, da1 = 0.f, dc1 = 0.f;
            #pragma unroll
            for (int i = 0; i < 16; ++i) {
                int   kj = pm[(seg << 4) + i];
                float w  = w1s[kj];
                float bb = b1s[kj];
                float2 v = *reinterpret_cast<const float2*>(&W2n[kj * 256 + d0]);
                vreg[i] = v;
                if (w < 0.f) {
                    ba0 = fmaf(v.x, w, ba0); bc0 = fmaf(v.x, bb, bc0);
                    ba1 = fmaf(v.y, w, ba1); bc1 = fmaf(v.y, bb, bc1);
                }
                float aw = fabsf(w);
                float cs = (w > 0.f) ? bb : -bb;
                da0 = fmaf(v.x, aw, da0); dc0 = fmaf(v.x, cs, dc0);
                da1 = fmaf(v.y, aw, da1); dc1 = fmaf(v.y, cs, dc1);
            }
            float* p = part[seg][prl];
            p[0] = ba0; p[1] = bc0; p[2] = ba1; p[3] = bc1;
            p[4] = da0; p[5] = dc0; p[6] = da1; p[7] = dc1;
        }
        __syncthreads();

        // phase 2: base totals + exclusive seg prefix (16 threads)
        if (tid < 16) {
            const int pr = tid;
            float sa0 = 0.f, sc0 = 0.f, sa1 = 0.f, sc1 = 0.f;
            #pragma unroll
            for (int sg = 0; sg < 16; ++sg) {
                const float* p = part[sg][pr];
                sa0 += p[0]; sc0 += p[1]; sa1 += p[2]; sc1 += p[3];
            }
            const int dd = ((strip << 4) + pr) << 1;
            sc0 += b2[n * 256 + dd];
            sc1 += b2[n * 256 + dd + 1];
            table[(size_t)n * 257 * 128 + ((strip << 4) + pr)] =
                make_uint2(pkh(sa0, sa1), pkh(sc0, sc1));
            float ra0 = sa0, rc0 = sc0, ra1 = sa1, rc1 = sc1;
            #pragma unroll
            for (int sg = 0; sg < 16; ++sg) {
                float* p = part[sg][pr];
                float t4 = p[4], t5 = p[5], t6 = p[6], t7 = p[7];
                p[0] = ra0; p[1] = rc0; p[2] = ra1; p[3] = rc1;
                ra0 += t4; rc0 += t5; ra1 += t6; rc1 += t7;
            }
        }
        __syncthreads();

        // phase 3: re-walk segment from cached regs, write 16 rows
        {
            const float* p = part[seg][prl];
            float a0 = p[0], c0 = p[1], a1 = p[2], c1 = p[3];
            uint2* trow = table + (size_t)n * 257 * 128 + prg;
            #pragma unroll
            for (int i = 0; i < 16; ++i) {
                int   j  = (seg << 4) + i;
                int   kj = pm[j];
                float w  = w1s[kj];
                float bb = b1s[kj];
                float2 v = vreg[i];
                float aw = fabsf(w);
                float cs = (w > 0.f) ? bb : -bb;
                a0 = fmaf(v.x, aw, a0); c0 = fmaf(v.x, cs, c0);
                a1 = fmaf(v.y, aw, a1); c1 = fmaf(v.y, cs, c1);
                trow[(size_t)(j + 1) * 128] = make_uint2(pkh(a0, a1), pkh(c0, c1));
            }
        }
    } else {
        // ================= sort role: (node, quarter) =================
        const int t = blk - 512;
        const int n = t >> 2;
        const int q = t & 3;

        float* kn = w1s;                 // reuse LDS
        kn[tid] = knots[n * 256 + tid];
        hist[tid] = 0;
        if (tid == 0) hist[256] = 0;
        __syncthreads();

        const float* Sn = S + ((size_t)n << 13) + (q << 11);
        float sv[8]; int iv[8];
        #pragma unroll
        for (int j = 0; j < 8; ++j) {
            const float s = Sn[tid + (j << 8)];
            sv[j] = s;
            int I = 0;
            #pragma unroll
            for (int step = 128; step >= 1; step >>= 1)
                if (kn[I + step - 1] < s) I += step;
            if (I < 256 && kn[I] < s) I += 1;
            iv[j] = I;
            atomicAdd(&hist[I], 1u);
        }
        __syncthreads();

        if (tid < 64) {
            int base = tid << 2;
            u32 h0 = hist[base], h1 = hist[base + 1], h2 = hist[base + 2], h3 = hist[base + 3];
            u32 lsum = h0 + h1 + h2 + h3;
            u32 run = lsum;
            #pragma unroll
            for (int off = 1; off < 64; off <<= 1) {
                u32 tt = __shfl_up(run, off, 64);
                if (lane >= off) run += tt;
            }
            u32 excl = run - lsum;
            hist[base]     = excl;
            hist[base + 1] = excl + h0;
            hist[base + 2] = excl + h0 + h1;
            hist[base + 3] = excl + h0 + h1 + h2;
            if (tid == 63) hist[256] = excl + lsum;
        }
        __syncthreads();

        uint2* dst = sorted + ((size_t)n << 13) + (q << 11);
        #pragma unroll
        for (int j = 0; j < 8; ++j) {
            u32 pos = atomicAdd(&hist[iv[j]], 1u);
            u32 bglob = (u32)((q << 11) + tid + (j << 8));
            dst[pos] = make_uint2(__float_as_uint(sv[j]), ((u32)iv[j] << 13) | bglob);
        }
    }
}

// ---------------------------------------------------------------------------
// K3: evaluate z. Block = 256 consecutive SORTED samples of one node.
// grid (64, 32). Inner: 64 x uint4 x {pk_fma, pk_max, dot2} in f16.
// ---------------------------------------------------------------------------
__global__ __launch_bounds__(256) void eval_nodes(
    const uint2* __restrict__ sorted, const uint2* __restrict__ table,
    const float* __restrict__ W3, const float* __restrict__ b3,
    float* __restrict__ Z)
{
    __shared__ u32 w3p[128];

    const int n   = blockIdx.x;
    const int c0  = blockIdx.y << 8;
    const int tid = threadIdx.x;

    if (tid < 128)
        w3p[tid] = pkh(W3[n * 256 + (tid << 1)], W3[n * 256 + (tid << 1) + 1]);
    __syncthreads();

    const uint2 ent = sorted[((size_t)n << 13) + c0 + tid];
    const float s   = __uint_as_float(ent.x);
    const int   I   = (int)(ent.y >> 13);
    const int   bl  = (int)(ent.y & 8191u);

    U32H s2; s2.u = pkh(s, s);
    const fp16x2 z2 = (fp16x2)0;

    const uint4* row = reinterpret_cast<const uint4*>(
        table + (size_t)((u32)n * 257 + I) * 128);   // 64 x uint4 = 4 d each

    float acc0 = 0.f, acc1 = 0.f;
    #pragma unroll 4
    for (int q = 0; q < 64; ++q) {
        uint4 v = row[q];
        uint2 w = reinterpret_cast<const uint2*>(w3p)[q];
        U32H a01{v.x}, b01{v.y}, a23{v.z}, b23{v.w};
        U32H h01, h23;
        h01.h = __builtin_elementwise_max(a01.h * s2.h + b01.h, z2);
        h23.h = __builtin_elementwise_max(a23.h * s2.h + b23.h, z2);
        acc0 = dot2f(h01.u, w.x, acc0);
        acc1 = dot2f(h23.u, w.y, acc1);
    }
    Z[((size_t)n << 13) + bl] = acc0 + acc1 + b3[n];
}

// ---------------------------------------------------------------------------
// K4: 65-way softmax, Z read via 64x64 LDS transpose (coalesced).
// ---------------------------------------------------------------------------
__global__ __launch_bounds__(256) void softmax_rows(
    const float* __restrict__ Q, const float* __restrict__ Y,
    const float* __restrict__ Z, const float* __restrict__ bias0,
    float* __restrict__ out)
{
    __shared__ float ts[64][65];
    const int b0   = blockIdx.x << 6;
    const int tid  = threadIdx.x;
    const int lane = tid & 63;
    const int wv   = tid >> 6;

    #pragma unroll
    for (int jj = 0; jj < 16; jj++) {
        int idx = tid + (jj << 8);
        int nn = idx >> 6, bb = idx & 63;
        ts[bb][nn] = Z[((size_t)nn << 13) + b0 + bb];
    }
    __syncthreads();

    const float bias = bias0[0];
    #pragma unroll 2
    for (int r = 0; r < 16; ++r) {
        const int row = (wv << 4) + r;
        const int b   = b0 + row;

        float s = Q[(size_t)b * 64 + lane] * Y[(size_t)b * 64 + lane];
        float ssum = s;
        #pragma unroll
        for (int mask = 32; mask >= 1; mask >>= 1) ssum += __shfl_xor(ssum, mask, 64);
        const float z0 = bias - ssum;

        float zl = ts[row][lane];
        float mx = zl;
        #pragma unroll
        for (int mask = 32; mask >= 1; mask >>= 1) mx = fmaxf(mx, __shfl_xor(mx, mask, 64));
        mx = fmaxf(mx, z0);

        float el = expf(zl - mx);
        float e0 = expf(z0 - mx);
        float den = el;
        #pragma unroll
        for (int mask = 32; mask >= 1; mask >>= 1) den += __shfl_xor(den, mask, 64);
        den += e0;
        const float inv = 1.0f / den;

        out[(size_t)b * 65 + 1 + lane] = el * inv;
        if (lane == 0) out[(size_t)b * 65] = e0 * inv;
    }
}

// ---------------------------------------------------------------------------
extern "C" void kernel_launch(void* const* d_in, const int* in_sizes, int n_in,
                              void* d_out, int out_size, void* d_ws, size_t ws_size,
                              hipStream_t stream)
{
    const float* Q     = (const float*)d_in[0];
    const float* Y     = (const float*)d_in[1];
    const float* W1    = (const float*)d_in[2];
    const float* b1    = (const float*)d_in[3];
    const float* W2    = (const float*)d_in[4];
    const float* b2    = (const float*)d_in[5];
    const float* W3    = (const float*)d_in[6];
    const float* b3    = (const float*)d_in[7];
    const float* bias0 = (const float*)d_in[8];
    float* out = (float*)d_out;

    // ws layout (bytes):
    // [0        ) table   64*257*128*8 = 16,842,752
    // [16842752 ) S       2,097,152
    // [18939904 ) Z       2,097,152
    // [21037056 ) knots   65,536
    // [21102592 ) perm    65,536
    // [21168128 ) sorted  64*8192*8 = 4,194,304    total 25,362,432
    char* ws = (char*)d_ws;
    uint2* table  = (uint2*)ws;
    float* S      = (float*)(ws + 16842752);
    float* Z      = (float*)(ws + 18939904);
    float* knots  = (float*)(ws + 21037056);
    int*   perm   = (int*)  (ws + 21102592);
    uint2* sorted = (uint2*)(ws + 21168128);

    prep<<<192, 256, 0, stream>>>(Q, Y, W1, b1, S, knots, perm);
    build_sort<<<768, 256, 0, stream>>>(W1, b1, W2, b2, perm, S, knots, table, sorted);
    eval_nodes<<<dim3(64, 32), 256, 0, stream>>>(sorted, table, W3, b3, Z);
    softmax_rows<<<128, 256, 0, stream>>>(Q, Y, Z, bias0, out);
}

// Round 20
// 54.976 us; speedup vs baseline: 1.1791x; 1.1791x over previous
//
#include <hip/hip_runtime.h>
#include <hip/hip_bf16.h>

// B=8192 rows, N=64 nodes, C=256. Per node: MLP 1->C->C->1 on s=Q*Y, then
// softmax over [z0, z_1..z_64]. Output f32 [B, 65].
//
// Round 20: EXACT interval compaction (all-f32, no f16 table).
// Per (node, interval I): each h_d = alpha_d s + beta_d is linear on I ->
//  - positive at both endpoints  => always active: fold into (A,B) partial
//  - non-positive at both        => drop (relu=0)
//  - else                        => "crossing": store {alpha,beta,w3} entry
// Eval: z = A*s+B + sum_crossings w3*relu(alpha*s+beta). Expected few
// crossings/interval -> eval ~30 ops vs 64x16B row walk.
// Deterministic: per-(n,I,strip) structures owned by one 16-lane group
// (DPP reduce + shfl prefix slots, exact cap 32, no atomics).

typedef unsigned int u32;

// sum across each 16-lane DPP row; every lane gets the row total (R4-proven)
__device__ __forceinline__ float row_reduce16(float x) {
    int v;
    v = __builtin_amdgcn_update_dpp(0, __float_as_int(x), 0xB1, 0xF, 0xF, false);  // quad_perm [1,0,3,2]
    x += __int_as_float(v);
    v = __builtin_amdgcn_update_dpp(0, __float_as_int(x), 0x4E, 0xF, 0xF, false);  // quad_perm [2,3,0,1]
    x += __int_as_float(v);
    v = __builtin_amdgcn_update_dpp(0, __float_as_int(x), 0x124, 0xF, 0xF, false); // row_ror:4
    x += __int_as_float(v);
    v = __builtin_amdgcn_update_dpp(0, __float_as_int(x), 0x128, 0xF, 0xF, false); // row_ror:8
    x += __int_as_float(v);
    return x;
}

// ---------------------------------------------------------------------------
// K1: prep. blocks 0..127: S[n][b] = Q[b][n]*Y[b][n] (64x64 LDS transpose).
//           blocks 128..191: knee s*_k = -b1_k/w1_k + bitonic sort.
// ---------------------------------------------------------------------------
__global__ __launch_bounds__(256) void prep(
    const float* __restrict__ Q, const float* __restrict__ Y,
    const float* __restrict__ W1, const float* __restrict__ b1,
    float* __restrict__ S, float* __restrict__ knots, int* __restrict__ perm)
{
    __shared__ float ts[64][65];
    __shared__ float key[256];
    __shared__ int   idx[256];

    const int blk = blockIdx.x;
    const int tid = threadIdx.x;

    if (blk < 128) {
        const int b0 = blk << 6;
        #pragma unroll
        for (int jj = 0; jj < 16; jj++) {
            int i = tid + (jj << 8);
            int r = i >> 6, c = i & 63;
            ts[r][c] = Q[(size_t)(b0 + r) * 64 + c] * Y[(size_t)(b0 + r) * 64 + c];
        }
        __syncthreads();
        #pragma unroll
        for (int jj = 0; jj < 16; jj++) {
            int i = tid + (jj << 8);
            int nn = i >> 6, bb = i & 63;
            S[((size_t)nn << 13) + b0 + bb] = ts[bb][nn];
        }
    } else {
        const int n = blk - 128;
        {
            float w = W1[n * 256 + tid];
            float b = b1[n * 256 + tid];
            key[tid] = -b / w;           // +-inf when w ~ 0: sorts to the ends
            idx[tid] = tid;
        }
        __syncthreads();
        for (int k = 2; k <= 256; k <<= 1) {
            for (int j = k >> 1; j > 0; j >>= 1) {
                int p = tid ^ j;
                if (p > tid) {
                    float a = key[tid], c = key[p];
                    bool up = ((tid & k) == 0);
                    if (up ? (a > c) : (a < c)) {
                        int ia = idx[tid];
                        key[tid] = c; idx[tid] = idx[p];
                        key[p] = a; idx[p] = ia;
                    }
                }
                __syncthreads();
            }
        }
        knots[n * 256 + tid] = key[tid];
        perm[n * 256 + tid]  = idx[tid];
    }
}

// ---------------------------------------------------------------------------
// K2: build_sort.
// blocks 0..511: scan + classify; (n = blk>>3, strip = blk&7), 256 thr =
//   (seg 0..15) x (pair 0..15). Writes AccP[n][I][strip] (float2),
//   cnt8[n][I][strip] (u8), entries[n][I][strip][<=32] (float4 {a,b,w3,0}).
// blocks 512..767: sort one (node, quarter) of samples by interval.
// ---------------------------------------------------------------------------
__global__ __launch_bounds__(256) void build_sort(
    const float* __restrict__ W1, const float* __restrict__ b1,
    const float* __restrict__ W2, const float* __restrict__ b2,
    const float* __restrict__ W3, const int* __restrict__ perm,
    const float* __restrict__ S, const float* __restrict__ knots,
    float4* __restrict__ entries, float2* __restrict__ AccP,
    unsigned char* __restrict__ cnt8, uint2* __restrict__ sorted)
{
    __shared__ float w1s[256], b1s[256], kns[256];
    __shared__ int   pm[256];
    __shared__ float part[16][16][8];
    __shared__ u32   hist[257];

    const int blk = blockIdx.x;
    const int tid = threadIdx.x;
    const int lane = tid & 63;

    if (blk < 512) {
        // ================= scan+classify role =================
        const int n    = blk >> 3;
        const int strip= blk & 7;
        const int prl  = tid & 15;
        const int seg  = tid >> 4;
        const int prg  = (strip << 4) + prl;
        const int d0   = prg << 1;

        w1s[tid] = W1[n * 256 + tid];
        b1s[tid] = b1[n * 256 + tid];
        kns[tid] = knots[n * 256 + tid];
        pm[tid]  = perm[n * 256 + tid];
        __syncthreads();

        const float w30 = W3[n * 256 + d0];
        const float w31 = W3[n * 256 + d0 + 1];
        const float* W2n = W2 + ((size_t)n << 16);
        float2 vreg[16];                 // phase-1 W2 cache, reused in phase 3

        // phase 1: per-segment partials (cache W2 loads in regs)
        {
            float ba0 = 0.f, bc0 = 0.f, ba1 = 0.f, bc1 = 0.f;
            float da0 = 0.f, dc0 = 0.f, da1 = 0.f, dc1 = 0.f;
            #pragma unroll
            for (int i = 0; i < 16; ++i) {
                int   kj = pm[(seg << 4) + i];
                float w  = w1s[kj];
                float bb = b1s[kj];
                float2 v = *reinterpret_cast<const float2*>(&W2n[kj * 256 + d0]);
                vreg[i] = v;
                if (w < 0.f) {
                    ba0 = fmaf(v.x, w, ba0); bc0 = fmaf(v.x, bb, bc0);
                    ba1 = fmaf(v.y, w, ba1); bc1 = fmaf(v.y, bb, bc1);
                }
                float aw = fabsf(w);
                float cs = (w > 0.f) ? bb : -bb;
                da0 = fmaf(v.x, aw, da0); dc0 = fmaf(v.x, cs, dc0);
                da1 = fmaf(v.y, aw, da1); dc1 = fmaf(v.y, cs, dc1);
            }
            float* p = part[seg][prl];
            p[0] = ba0; p[1] = bc0; p[2] = ba1; p[3] = bc1;
            p[4] = da0; p[5] = dc0; p[6] = da1; p[7] = dc1;
        }
        __syncthreads();

        // phase 2 (16 threads = lanes 0..15): base totals, classify I=0,
        // then seed per-segment start values.
        if (tid < 16) {
            const int pr = tid;
            float sa0 = 0.f, sc0 = 0.f, sa1 = 0.f, sc1 = 0.f;
            #pragma unroll
            for (int sg = 0; sg < 16; ++sg) {
                const float* p = part[sg][pr];
                sa0 += p[0]; sc0 += p[1]; sa1 += p[2]; sc1 += p[3];
            }
            const int dd = ((strip << 4) + pr) << 1;
            sc0 += b2[n * 256 + dd];
            sc1 += b2[n * 256 + dd + 1];

            // classify interval I=0 on (-inf, kns[0]]
            float k0 = kns[0];
            float hLo0 = (sa0 != 0.f) ? -sa0 : sc0;     // sign proxy at -inf
            float hHi0 = fmaf(sa0, k0, sc0);
            float hLo1 = (sa1 != 0.f) ? -sa1 : sc1;
            float hHi1 = fmaf(sa1, k0, sc1);
            bool act0 = hLo0 > 0.f && hHi0 > 0.f, drp0 = hLo0 <= 0.f && hHi0 <= 0.f;
            bool act1 = hLo1 > 0.f && hHi1 > 0.f, drp1 = hLo1 <= 0.f && hHi1 <= 0.f;
            bool cr0 = !act0 && !drp0, cr1 = !act1 && !drp1;
            float As = (act0 ? w30 * sa0 : 0.f) + (act1 ? w31 * sa1 : 0.f);
            float Bs = (act0 ? w30 * sc0 : 0.f) + (act1 ? w31 * sc1 : 0.f);
            As = row_reduce16(As); Bs = row_reduce16(Bs);
            u32 cx = (u32)cr0 + (u32)cr1;
            u32 incl = cx, t;
            t = __shfl_up(incl, 1, 64); if (pr >= 1) incl += t;
            t = __shfl_up(incl, 2, 64); if (pr >= 2) incl += t;
            t = __shfl_up(incl, 4, 64); if (pr >= 4) incl += t;
            t = __shfl_up(incl, 8, 64); if (pr >= 8) incl += t;
            u32 excl = incl - cx;
            u32 tot  = __shfl(incl, 15, 64);
            size_t ib = (size_t)(n * 257 + 0) * 8 + strip;
            size_t eb = ib * 32;
            u32 off = excl;
            if (cr0) { entries[eb + off] = make_float4(sa0, sc0, w30, 0.f); off++; }
            if (cr1) { entries[eb + off] = make_float4(sa1, sc1, w31, 0.f); }
            if (pr == 0) {
                AccP[ib] = make_float2(As, Bs);
                cnt8[ib] = (unsigned char)tot;
            }

            float ra0 = sa0, rc0 = sc0, ra1 = sa1, rc1 = sc1;
            #pragma unroll
            for (int sg = 0; sg < 16; ++sg) {
                float* p = part[sg][pr];
                float t4 = p[4], t5 = p[5], t6 = p[6], t7 = p[7];
                p[0] = ra0; p[1] = rc0; p[2] = ra1; p[3] = rc1;
                ra0 += t4; rc0 += t5; ra1 += t6; rc1 += t7;
            }
        }
        __syncthreads();

        // phase 3: re-walk segment; classify each row I=j+1, emit structures
        {
            const float* p = part[seg][prl];
            float a0 = p[0], c0 = p[1], a1 = p[2], c1 = p[3];
            #pragma unroll 4
            for (int i = 0; i < 16; ++i) {
                int   j  = (seg << 4) + i;
                int   kj = pm[j];
                float w  = w1s[kj];
                float bb = b1s[kj];
                float2 v = vreg[i];
                float aw = fabsf(w);
                float cs = (w > 0.f) ? bb : -bb;
                a0 = fmaf(v.x, aw, a0); c0 = fmaf(v.x, cs, c0);
                a1 = fmaf(v.y, aw, a1); c1 = fmaf(v.y, cs, c1);

                // interval I=j+1 on [kns[j], kns[j+1]] (j=255: hi=+inf)
                float lo = kns[j];
                float hLo0 = fmaf(a0, lo, c0), hLo1 = fmaf(a1, lo, c1);
                float hHi0, hHi1;
                if (j < 255) {
                    float hi = kns[j + 1];
                    hHi0 = fmaf(a0, hi, c0); hHi1 = fmaf(a1, hi, c1);
                } else {
                    hHi0 = (a0 != 0.f) ? a0 : c0;     // sign proxy at +inf
                    hHi1 = (a1 != 0.f) ? a1 : c1;
                }
                bool act0 = hLo0 > 0.f && hHi0 > 0.f, drp0 = hLo0 <= 0.f && hHi0 <= 0.f;
                bool act1 = hLo1 > 0.f && hHi1 > 0.f, drp1 = hLo1 <= 0.f && hHi1 <= 0.f;
                bool cr0 = !act0 && !drp0, cr1 = !act1 && !drp1;
                float As = (act0 ? w30 * a0 : 0.f) + (act1 ? w31 * a1 : 0.f);
                float Bs = (act0 ? w30 * c0 : 0.f) + (act1 ? w31 * c1 : 0.f);
                As = row_reduce16(As); Bs = row_reduce16(Bs);
                u32 cx = (u32)cr0 + (u32)cr1;
                u32 incl = cx, t;
                t = __shfl_up(incl, 1, 64); if (prl >= 1) incl += t;
                t = __shfl_up(incl, 2, 64); if (prl >= 2) incl += t;
                t = __shfl_up(incl, 4, 64); if (prl >= 4) incl += t;
                t = __shfl_up(incl, 8, 64); if (prl >= 8) incl += t;
                u32 excl = incl - cx;
                u32 tot  = __shfl(incl, (lane & ~15) + 15, 64);
                size_t ib = (size_t)(n * 257 + (j + 1)) * 8 + strip;
                size_t eb = ib * 32;
                u32 off = excl;
                if (cr0) { entries[eb + off] = make_float4(a0, c0, w30, 0.f); off++; }
                if (cr1) { entries[eb + off] = make_float4(a1, c1, w31, 0.f); }
                if (prl == 0) {
                    AccP[ib] = make_float2(As, Bs);
                    cnt8[ib] = (unsigned char)tot;
                }
            }
        }
    } else {
        // ================= sort role: (node, quarter) =================
        const int t = blk - 512;
        const int n = t >> 2;
        const int q = t & 3;

        float* kn = w1s;                 // reuse LDS
        kn[tid] = knots[n * 256 + tid];
        hist[tid] = 0;
        if (tid == 0) hist[256] = 0;
        __syncthreads();

        const float* Sn = S + ((size_t)n << 13) + (q << 11);
        float sv[8]; int iv[8];
        #pragma unroll
        for (int j = 0; j < 8; ++j) {
            const float s = Sn[tid + (j << 8)];
            sv[j] = s;
            int I = 0;
            #pragma unroll
            for (int step = 128; step >= 1; step >>= 1)
                if (kn[I + step - 1] < s) I += step;
            if (I < 256 && kn[I] < s) I += 1;
            iv[j] = I;
            atomicAdd(&hist[I], 1u);
        }
        __syncthreads();

        if (tid < 64) {
            int base = tid << 2;
            u32 h0 = hist[base], h1 = hist[base + 1], h2 = hist[base + 2], h3 = hist[base + 3];
            u32 lsum = h0 + h1 + h2 + h3;
            u32 run = lsum;
            #pragma unroll
            for (int off = 1; off < 64; off <<= 1) {
                u32 tt = __shfl_up(run, off, 64);
                if (lane >= off) run += tt;
            }
            u32 excl = run - lsum;
            hist[base]     = excl;
            hist[base + 1] = excl + h0;
            hist[base + 2] = excl + h0 + h1;
            hist[base + 3] = excl + h0 + h1 + h2;
            if (tid == 63) hist[256] = excl + lsum;
        }
        __syncthreads();

        uint2* dst = sorted + ((size_t)n << 13) + (q << 11);
        #pragma unroll
        for (int j = 0; j < 8; ++j) {
            u32 pos = atomicAdd(&hist[iv[j]], 1u);
            u32 bglob = (u32)((q << 11) + tid + (j << 8));
            dst[pos] = make_uint2(__float_as_uint(sv[j]), ((u32)iv[j] << 13) | bglob);
        }
    }
}

// ---------------------------------------------------------------------------
// K3: evaluate z. Block = 256 consecutive SORTED samples of one node.
// grid (64, 32). z = A*s+B + sum over crossing entries.
// ---------------------------------------------------------------------------
__global__ __launch_bounds__(256) void eval_nodes(
    const uint2* __restrict__ sorted, const float4* __restrict__ entries,
    const float2* __restrict__ AccP, const unsigned char* __restrict__ cnt8,
    const float* __restrict__ b3, float* __restrict__ Z)
{
    const int n   = blockIdx.x;
    const int c0  = blockIdx.y << 8;
    const int tid = threadIdx.x;

    const uint2 ent = sorted[((size_t)n << 13) + c0 + tid];
    const float s   = __uint_as_float(ent.x);
    const int   I   = (int)(ent.y >> 13);
    const int   bl  = (int)(ent.y & 8191u);

    const size_t base = (size_t)(n * 257 + I) * 8;

    float A = 0.f, B = 0.f;
    #pragma unroll
    for (int k = 0; k < 8; ++k) {
        float2 t = AccP[base + k];
        A += t.x; B += t.y;
    }
    float z = fmaf(A, s, B);

    const uint2 cc = *reinterpret_cast<const uint2*>(&cnt8[base]);
    #pragma unroll
    for (int st = 0; st < 8; ++st) {
        u32 c = (st < 4) ? ((cc.x >> (st * 8)) & 0xFFu)
                         : ((cc.y >> ((st - 4) * 8)) & 0xFFu);
        const float4* ep = entries + ((base + st) << 5);
        for (u32 jj = 0; jj < c; ++jj) {
            float4 e = ep[jj];
            z = fmaf(e.z, fmaxf(fmaf(e.x, s, e.y), 0.f), z);
        }
    }
    Z[((size_t)n << 13) + bl] = z + b3[n];
}

// ---------------------------------------------------------------------------
// K4: 65-way softmax, Z read via 64x64 LDS transpose (coalesced).
// ---------------------------------------------------------------------------
__global__ __launch_bounds__(256) void softmax_rows(
    const float* __restrict__ Q, const float* __restrict__ Y,
    const float* __restrict__ Z, const float* __restrict__ bias0,
    float* __restrict__ out)
{
    __shared__ float ts[64][65];
    const int b0   = blockIdx.x << 6;
    const int tid  = threadIdx.x;
    const int lane = tid & 63;
    const int wv   = tid >> 6;

    #pragma unroll
    for (int jj = 0; jj < 16; jj++) {
        int idx = tid + (jj << 8);
        int nn = idx >> 6, bb = idx & 63;
        ts[bb][nn] = Z[((size_t)nn << 13) + b0 + bb];
    }
    __syncthreads();

    const float bias = bias0[0];
    #pragma unroll 2
    for (int r = 0; r < 16; ++r) {
        const int row = (wv << 4) + r;
        const int b   = b0 + row;

        float s = Q[(size_t)b * 64 + lane] * Y[(size_t)b * 64 + lane];
        float ssum = s;
        #pragma unroll
        for (int mask = 32; mask >= 1; mask >>= 1) ssum += __shfl_xor(ssum, mask, 64);
        const float z0 = bias - ssum;

        float zl = ts[row][lane];
        float mx = zl;
        #pragma unroll
        for (int mask = 32; mask >= 1; mask >>= 1) mx = fmaxf(mx, __shfl_xor(mx, mask, 64));
        mx = fmaxf(mx, z0);

        float el = expf(zl - mx);
        float e0 = expf(z0 - mx);
        float den = el;
        #pragma unroll
        for (int mask = 32; mask >= 1; mask >>= 1) den += __shfl_xor(den, mask, 64);
        den += e0;
        const float inv = 1.0f / den;

        out[(size_t)b * 65 + 1 + lane] = el * inv;
        if (lane == 0) out[(size_t)b * 65] = e0 * inv;
    }
}

// ---------------------------------------------------------------------------
extern "C" void kernel_launch(void* const* d_in, const int* in_sizes, int n_in,
                              void* d_out, int out_size, void* d_ws, size_t ws_size,
                              hipStream_t stream)
{
    const float* Q     = (const float*)d_in[0];
    const float* Y     = (const float*)d_in[1];
    const float* W1    = (const float*)d_in[2];
    const float* b1    = (const float*)d_in[3];
    const float* W2    = (const float*)d_in[4];
    const float* b2    = (const float*)d_in[5];
    const float* W3    = (const float*)d_in[6];
    const float* b3    = (const float*)d_in[7];
    const float* bias0 = (const float*)d_in[8];
    float* out = (float*)d_out;

    // ws layout (bytes):
    // [0        ) entries 64*257*8*32*16 = 67,371,008
    // [67371008 ) AccP    64*257*8*8    =  1,052,672
    // [68423680 ) cnt8    64*257*8      =    131,584
    // [68555264 ) S       2,097,152
    // [70652416 ) Z       2,097,152
    // [72749568 ) knots   65,536
    // [72815104 ) perm    65,536
    // [72880640 ) sorted  4,194,304     total 77,074,944
    char* ws = (char*)d_ws;
    float4* entries      = (float4*)ws;
    float2* AccP         = (float2*)(ws + 67371008);
    unsigned char* cnt8  = (unsigned char*)(ws + 68423680);
    float* S             = (float*)(ws + 68555264);
    float* Z             = (float*)(ws + 70652416);
    float* knots         = (float*)(ws + 72749568);
    int*   perm          = (int*)  (ws + 72815104);
    uint2* sorted        = (uint2*)(ws + 72880640);

    prep<<<192, 256, 0, stream>>>(Q, Y, W1, b1, S, knots, perm);
    build_sort<<<768, 256, 0, stream>>>(W1, b1, W2, b2, W3, perm, S, knots,
                                        entries, AccP, cnt8, sorted);
    eval_nodes<<<dim3(64, 32), 256, 0, stream>>>(sorted, entries, AccP, cnt8, b3, Z);
    softmax_rows<<<128, 256, 0, stream>>>(Q, Y, Z, bias0, out);
}